// Round 7
// baseline (128.496 us; speedup 1.0000x reference)
//
#include <hip/hip_runtime.h>
#include <math.h>

#define EPS 1e-8f
#define LAMBDA 1e-3f
#define LOG2E 1.44269504088896f

typedef float f2 __attribute__((ext_vector_type(2)));
typedef unsigned int u32v2 __attribute__((ext_vector_type(2)));
__device__ __forceinline__ f2 f2s(float x) { return (f2){x, x}; }
__device__ __forceinline__ f2 pkfma(f2 a, f2 b, f2 c) {
  return __builtin_elementwise_fma(a, b, c);
}

// DPP lane-permute: executes in the VALU pipe (no LDS round trip).
template <int CTRL>
__device__ __forceinline__ float dppmov(float v) {
  return __int_as_float(__builtin_amdgcn_update_dpp(
      0, __float_as_int(v), CTRL, 0xF, 0xF, true));
}

// xor16 / xor32 lane exchanges. gfx950 permlane*_swap are VALU instructions
// (no LDS pipe); ds_swizzle/shfl fallbacks keep the code portable.
#if __has_builtin(__builtin_amdgcn_permlane16_swap)
__device__ __forceinline__ float sum_x16(float v) {
  u32v2 r = __builtin_amdgcn_permlane16_swap(__float_as_uint(v), __float_as_uint(v), false, false);
  return __uint_as_float(r.x) + __uint_as_float(r.y);
}
__device__ __forceinline__ float max_x16(float v) {
  u32v2 r = __builtin_amdgcn_permlane16_swap(__float_as_uint(v), __float_as_uint(v), false, false);
  return fmaxf(__uint_as_float(r.x), __uint_as_float(r.y));
}
#else
__device__ __forceinline__ float sum_x16(float v) {
  return v + __int_as_float(__builtin_amdgcn_ds_swizzle(__float_as_int(v), 0x401F));
}
__device__ __forceinline__ float max_x16(float v) {
  return fmaxf(v, __int_as_float(__builtin_amdgcn_ds_swizzle(__float_as_int(v), 0x401F)));
}
#endif
#if __has_builtin(__builtin_amdgcn_permlane32_swap)
__device__ __forceinline__ float sum_x32(float v) {
  u32v2 r = __builtin_amdgcn_permlane32_swap(__float_as_uint(v), __float_as_uint(v), false, false);
  return __uint_as_float(r.x) + __uint_as_float(r.y);
}
#else
__device__ __forceinline__ float sum_x32(float v) { return v + __shfl_xor(v, 32, 64); }
#endif

__device__ __forceinline__ float redsum32(float v) {
  v += dppmov<0xB1>(v);    // xor 1 (quad_perm)
  v += dppmov<0x4E>(v);    // xor 2 (quad_perm)
  v += dppmov<0x141>(v);   // xor 7 (row_half_mirror)
  v += dppmov<0x140>(v);   // xor 15 (row_mirror)
  return sum_x16(v);       // xor 16 (permlane16_swap: VALU)
}
__device__ __forceinline__ float redmax32(float v) {
  v = fmaxf(v, dppmov<0xB1>(v));
  v = fmaxf(v, dppmov<0x4E>(v));
  v = fmaxf(v, dppmov<0x141>(v));
  v = fmaxf(v, dppmov<0x140>(v));
  return max_x16(v);
}

// 4x4 pose matmul on packed f2 lanes: v2[8] = x(4x4) @ w(4x4), row-major.
__device__ __forceinline__ void mat8(const float* __restrict__ xrow,
                                     float4 w0, float4 w1, float4 w2, float4 w3,
                                     f2 (&v2)[8]) {
  const float4* xp = reinterpret_cast<const float4*>(xrow);
  float4 xv0 = xp[0], xv1 = xp[1], xv2_ = xp[2], xv3 = xp[3];
  f2 w0a = {w0.x, w0.y}, w0b = {w0.z, w0.w};
  f2 w1a = {w1.x, w1.y}, w1b = {w1.z, w1.w};
  f2 w2a = {w2.x, w2.y}, w2b = {w2.z, w2.w};
  f2 w3a = {w3.x, w3.y}, w3b = {w3.z, w3.w};
  {
    f2 ta = f2s(xv0.x) * w0a; f2 tb = f2s(xv0.x) * w0b;
    ta = pkfma(f2s(xv0.y), w1a, ta); tb = pkfma(f2s(xv0.y), w1b, tb);
    ta = pkfma(f2s(xv0.z), w2a, ta); tb = pkfma(f2s(xv0.z), w2b, tb);
    v2[0] = pkfma(f2s(xv0.w), w3a, ta); v2[1] = pkfma(f2s(xv0.w), w3b, tb);
  }
  {
    f2 ta = f2s(xv1.x) * w0a; f2 tb = f2s(xv1.x) * w0b;
    ta = pkfma(f2s(xv1.y), w1a, ta); tb = pkfma(f2s(xv1.y), w1b, tb);
    ta = pkfma(f2s(xv1.z), w2a, ta); tb = pkfma(f2s(xv1.z), w2b, tb);
    v2[2] = pkfma(f2s(xv1.w), w3a, ta); v2[3] = pkfma(f2s(xv1.w), w3b, tb);
  }
  {
    f2 ta = f2s(xv2_.x) * w0a; f2 tb = f2s(xv2_.x) * w0b;
    ta = pkfma(f2s(xv2_.y), w1a, ta); tb = pkfma(f2s(xv2_.y), w1b, tb);
    ta = pkfma(f2s(xv2_.z), w2a, ta); tb = pkfma(f2s(xv2_.z), w2b, tb);
    v2[4] = pkfma(f2s(xv2_.w), w3a, ta); v2[5] = pkfma(f2s(xv2_.w), w3b, tb);
  }
  {
    f2 ta = f2s(xv3.x) * w0a; f2 tb = f2s(xv3.x) * w0b;
    ta = pkfma(f2s(xv3.y), w1a, ta); tb = pkfma(f2s(xv3.y), w1b, tb);
    ta = pkfma(f2s(xv3.z), w2a, ta); tb = pkfma(f2s(xv3.z), w2b, tb);
    v2[6] = pkfma(f2s(xv3.w), w3a, ta); v2[7] = pkfma(f2s(xv3.w), w3b, tb);
  }
}

// One block per output row n (508 rows). 512 threads = 16 chunks x 32 c.
// Thread (chunk,c) owns output capsule c for B in [chunk*18, chunk*18+18).
//
// w prefetch depth 2 with only two banks: the bank reload is issued
// IMMEDIATELY after the mat8 that consumes it, targeting i+2 -> in-flight
// window ~1.8 iterations (~250cy) > L2 hit latency (~200cy). No staging
// temps (round-6's n0..n3 removed).
//
// Per-iteration softmax reduce is pure VALU (DPP + permlane16_swap);
// finalize's cross-half pre-reduce uses permlane32_swap. Zero LDS ops in
// the iteration-serial chain.
//
// launch_bounds(512, 2): caps VGPR at 128 (2 blocks/CU); (512,4) forced an
// effective 64-cap and spilled (rounds 0-2). Spills show as WRITE_SIZE
// above the 19.4 MB output floor.
__launch_bounds__(512, 2)
__global__ void convcaps_kernel(const float* __restrict__ x,
                                const float* __restrict__ wgl,
                                const float* __restrict__ beta_u,
                                const float* __restrict__ beta_a,
                                float* __restrict__ out) {
  __shared__ float xr[288][16];       // pose patches, 18 KB
  __shared__ float a_sh[288];         // a/(a+EPS)
  __shared__ float red[33][256];      // per-wave partials (A1[16],A2[16],S)
  __shared__ float mu_l[32][18];      // +2 pad: rows 8B-aligned for b64 reads
  __shared__ float i2s_l[32][18];     // LOG2E/(2*sigma)
  __shared__ float hl_l[32][18];      // 0.5*ln(sigma)
  __shared__ float S_l[32];
  __shared__ float aout_l[32];
  __shared__ float lnao_l[32];

  const int tid = threadIdx.x;
  const int n = blockIdx.x;
  const int c = tid & 31;
  const int chunk = tid >> 5;         // 0..15

  // ---- stage 9 source rows (float4): xr[B][s], a_sh[B] ----
  for (int idx = tid; idx < 1224; idx += 512) {   // 9 * 136 float4
    int t = idx / 136;
    int e4 = idx - t * 136;
    int g = 9 * n + t;
    int bg = g / 2286;                 // 2286 = 9*254
    int ki = (g % 2286) / 762;         // 762 = 3*254
    int owp = g % 254;
    const float4* src = reinterpret_cast<const float4*>(x) +
                        (size_t)((bg * 256 + ki + owp) * 4) * 136;
    float4 val = src[e4];
    if (e4 < 128) reinterpret_cast<float4*>(&xr[0][0])[t * 128 + e4] = val;
    else          reinterpret_cast<float4*>(a_sh)[t * 8 + (e4 - 128)] = val;
  }
  __syncthreads();
  for (int e = tid; e < 288; e += 512) { float a = a_sh[e]; a_sh[e] = a / (a + EPS); }
  __syncthreads();

  f2 A1[8], A2[8];
  float Ssum;
  f2 m2[8], i2s2[8];                  // m2 = -2*mu*i2s; i2s pre-scaled LOG2E
  float bias3 = 0.f;
  const int Bbase = chunk * 18;
  const float4* wp = reinterpret_cast<const float4*>(wgl) + ((size_t)(Bbase * 32 + c)) * 4;
  float* rowout = out + 276352 + ((size_t)n * 288 + Bbase) * 32 + c;   // r output

  auto ldw = [&](int i, float4& b0, float4& b1, float4& b2, float4& b3) {
    const float4* nx = wp + (size_t)i * 128;
    b0 = nx[0]; b1 = nx[1]; b2 = nx[2]; b3 = nx[3];
  };

  auto accum = [&](const f2 (&v2)[8], float wgt) {
    f2 wg = f2s(wgt);
    #pragma unroll
    for (int j = 0; j < 8; ++j) {
      f2 p = wg * v2[j];
      A1[j] += p;
      A2[j] = pkfma(p, v2[j], A2[j]);
    }
    Ssum += wgt;
  };

  auto qexp = [&](const f2 (&v2)[8]) -> float {
    f2 qa = {0.f, 0.f}, qb = {0.f, 0.f};
    #pragma unroll
    for (int j = 0; j < 8; j += 2) {
      f2 t0 = pkfma(v2[j], i2s2[j], m2[j]);
      qa = pkfma(v2[j], t0, qa);
      f2 t1 = pkfma(v2[j + 1], i2s2[j + 1], m2[j + 1]);
      qb = pkfma(v2[j + 1], t1, qb);
    }
    float acc = (qa.x + qb.x) + (qa.y + qb.y);
    float lnap = bias3 - acc;           // <= 0, log2 domain
    float e;
    asm("v_exp_f32 %0, %1" : "=v"(e) : "v"(lnap));
    return e;
  };

  auto finalize = [&]() {
    // cross-half pre-reduce: permlane32_swap (VALU), then LDS across 8 waves
    #pragma unroll
    for (int j = 0; j < 8; ++j) {
      A1[j].x = sum_x32(A1[j].x);
      A1[j].y = sum_x32(A1[j].y);
      A2[j].x = sum_x32(A2[j].x);
      A2[j].y = sum_x32(A2[j].y);
    }
    Ssum = sum_x32(Ssum);
    if ((tid & 63) < 32) {
      int col = (tid >> 6) * 32 + c;
      #pragma unroll
      for (int j = 0; j < 8; ++j) {
        red[2 * j][col] = A1[j].x;
        red[2 * j + 1][col] = A1[j].y;
        red[16 + 2 * j][col] = A2[j].x;
        red[17 + 2 * j][col] = A2[j].y;
      }
      red[32][col] = Ssum;
    }
    __syncthreads();
    {
      int s = tid >> 5;
      int c2 = tid & 31;
      float a1 = 0.f, a2 = 0.f, ss = 0.f;
      #pragma unroll
      for (int ch = 0; ch < 8; ++ch) {
        int col = ch * 32 + c2;
        a1 += red[s][col];
        a2 += red[16 + s][col];
        ss += red[32][col];
      }
      float inv = __builtin_amdgcn_rcpf(ss + EPS);
      float m = a1 * inv;
      float Sc = ss * inv;
      float sg = fmaf(-m * m, 2.0f - Sc, a2 * inv) + EPS;   // sigma_sq
      mu_l[c2][s] = m;
      i2s_l[c2][s] = (0.5f * LOG2E) * __builtin_amdgcn_rcpf(sg);  // log2 domain
      hl_l[c2][s] = 0.5f * __logf(sg);
      if (s == 0) S_l[c2] = ss;
    }
    __syncthreads();
    if (tid < 32) {
      float sh = 0.f;
      #pragma unroll
      for (int s = 0; s < 16; ++s) sh += hl_l[tid][s];
      float cost = fmaf(beta_u[tid], 16.0f, sh) * S_l[tid];
      float z = LAMBDA * (beta_a[tid] - cost);
      float ao = __builtin_amdgcn_rcpf(1.0f + __expf(-z));
      aout_l[tid] = ao;
      lnao_l[tid] = __logf(ao);
    }
    __syncthreads();
  };

  float4 wa0, wa1, wa2, wa3, wb0, wb1, wb2, wb3;

  // ================= pass 0: wgt = a/32, no softmax =================
  {
    #pragma unroll
    for (int j = 0; j < 8; ++j) { A1[j] = (f2){0.f, 0.f}; A2[j] = (f2){0.f, 0.f}; }
    Ssum = 0.f;
    ldw(0, wa0, wa1, wa2, wa3);
    ldw(1, wb0, wb1, wb2, wb3);
    for (int pr = 0; pr < 8; ++pr) {
      const int i0 = 2 * pr, i1 = i0 + 1;
      f2 v2[8];
      mat8(&xr[Bbase + i0][0], wa0, wa1, wa2, wa3, v2);
      ldw(i0 + 2, wa0, wa1, wa2, wa3);          // depth-2 reload into freed bank
      accum(v2, a_sh[Bbase + i0] * 0.03125f);
      mat8(&xr[Bbase + i1][0], wb0, wb1, wb2, wb3, v2);
      ldw(i1 + 2, wb0, wb1, wb2, wb3);
      accum(v2, a_sh[Bbase + i1] * 0.03125f);
    }
    {   // i = 16 (wa), i = 17 (wb): no more prefetch
      f2 v2[8];
      mat8(&xr[Bbase + 16][0], wa0, wa1, wa2, wa3, v2);
      accum(v2, a_sh[Bbase + 16] * 0.03125f);
      mat8(&xr[Bbase + 17][0], wb0, wb1, wb2, wb3, v2);
      accum(v2, a_sh[Bbase + 17] * 0.03125f);
    }
    finalize();
  }

  // ================= passes 1,2: pipelined softmax loop =================
  for (int pass = 1; pass < 3; ++pass) {
    #pragma unroll
    for (int j = 0; j < 8; ++j) { A1[j] = (f2){0.f, 0.f}; A2[j] = (f2){0.f, 0.f}; }
    Ssum = 0.f;
    {
      const f2* murow = reinterpret_cast<const f2*>(&mu_l[c][0]);
      const f2* isrow = reinterpret_cast<const f2*>(&i2s_l[c][0]);
      f2 kacc = {0.f, 0.f};
      float Hl = 0.f;
      #pragma unroll
      for (int j = 0; j < 8; ++j) {
        f2 mu = murow[j];
        f2 is = isrow[j];
        i2s2[j] = is;
        f2 mis = mu * is;
        m2[j] = f2s(-2.f) * mis;
        kacc = pkfma(mis, mu, kacc);        // sum mu^2*i2s (log2 domain)
        Hl += hl_l[c][2 * j] + hl_l[c][2 * j + 1];
      }
      float bias = lnao_l[c] - Hl;
      bias -= redmax32(bias);               // once per pass: lnap <= 0 always
      bias3 = bias * LOG2E - (kacc.x + kacc.y);
    }
    const bool doStore = (pass == 2);

    ldw(0, wa0, wa1, wa2, wa3);
    ldw(1, wb0, wb1, wb2, wb3);
    f2 vA[8], vB[8];
    float wgtA, wgtB;

    // prologue: i = 0 (even -> wa)
    {
      mat8(&xr[Bbase][0], wa0, wa1, wa2, wa3, vA);
      ldw(2, wa0, wa1, wa2, wa3);
      float af = a_sh[Bbase];
      float e = qexp(vA);
      float se = redsum32(e);
      float t = __builtin_amdgcn_rcpf(se + 1e-35f);
      float r2 = e * t;
      if (doStore) rowout[0] = r2;
      wgtA = r2 * af;
    }
    for (int pr = 0; pr < 7; ++pr) {
      const int iB = 2 * pr + 1, iC = iB + 1;
      {   // odd iteration: wb
        mat8(&xr[Bbase + iB][0], wb0, wb1, wb2, wb3, vB);
        ldw(iB + 2, wb0, wb1, wb2, wb3);
        float af = a_sh[Bbase + iB];
        float e = qexp(vB);
        float se = redsum32(e);
        accum(vA, wgtA);                    // fills the reduce's dep shadow
        float t = __builtin_amdgcn_rcpf(se + 1e-35f);
        float r2 = e * t;
        if (doStore) rowout[(size_t)iB * 32] = r2;
        wgtB = r2 * af;
      }
      {   // even iteration: wa
        mat8(&xr[Bbase + iC][0], wa0, wa1, wa2, wa3, vA);
        ldw(iC + 2, wa0, wa1, wa2, wa3);
        float af = a_sh[Bbase + iC];
        float e = qexp(vA);
        float se = redsum32(e);
        accum(vB, wgtB);
        float t = __builtin_amdgcn_rcpf(se + 1e-35f);
        float r2 = e * t;
        if (doStore) rowout[(size_t)iC * 32] = r2;
        wgtA = r2 * af;
      }
    }
    // i = 15 (wb; reload 17 into wb)
    {
      mat8(&xr[Bbase + 15][0], wb0, wb1, wb2, wb3, vB);
      ldw(17, wb0, wb1, wb2, wb3);
      float af = a_sh[Bbase + 15];
      float e = qexp(vB);
      float se = redsum32(e);
      accum(vA, wgtA);
      float t = __builtin_amdgcn_rcpf(se + 1e-35f);
      float r2 = e * t;
      if (doStore) rowout[(size_t)15 * 32] = r2;
      wgtB = r2 * af;
    }
    // i = 16 (wa, no prefetch)
    {
      mat8(&xr[Bbase + 16][0], wa0, wa1, wa2, wa3, vA);
      float af = a_sh[Bbase + 16];
      float e = qexp(vA);
      float se = redsum32(e);
      accum(vB, wgtB);
      float t = __builtin_amdgcn_rcpf(se + 1e-35f);
      float r2 = e * t;
      if (doStore) rowout[(size_t)16 * 32] = r2;
      wgtA = r2 * af;
    }
    // i = 17 (wb)
    {
      mat8(&xr[Bbase + 17][0], wb0, wb1, wb2, wb3, vB);
      float af = a_sh[Bbase + 17];
      float e = qexp(vB);
      float se = redsum32(e);
      accum(vA, wgtA);
      float t = __builtin_amdgcn_rcpf(se + 1e-35f);
      float r2 = e * t;
      if (doStore) rowout[(size_t)17 * 32] = r2;
      wgtB = r2 * af;
      accum(vB, wgtB);
    }
    finalize();
  }

  // ---- outputs: row n = [mu (512) | a_out (32)], coalesced ----
  {
    int c2 = tid >> 4;
    int s = tid & 15;
    out[(size_t)n * 544 + tid] = mu_l[c2][s];
  }
  if (tid < 32) out[(size_t)n * 544 + 512 + tid] = aout_l[tid];
}

extern "C" void kernel_launch(void* const* d_in, const int* in_sizes, int n_in,
                              void* d_out, int out_size, void* d_ws, size_t ws_size,
                              hipStream_t stream) {
  const float* x  = (const float*)d_in[0];
  const float* w  = (const float*)d_in[1];
  const float* bu = (const float*)d_in[2];
  const float* ba = (const float*)d_in[3];
  float* out = (float*)d_out;
  convcaps_kernel<<<dim3(508), dim3(512), 0, stream>>>(x, w, bu, ba, out);
}

// Round 8
// 126.139 us; speedup vs baseline: 1.0187x; 1.0187x over previous
//
#include <hip/hip_runtime.h>
#include <math.h>

#define EPS 1e-8f
#define LAMBDA 1e-3f
#define LOG2E 1.44269504088896f

typedef float f2 __attribute__((ext_vector_type(2)));
typedef unsigned int u32v2 __attribute__((ext_vector_type(2)));
__device__ __forceinline__ f2 f2s(float x) { return (f2){x, x}; }
__device__ __forceinline__ f2 pkfma(f2 a, f2 b, f2 c) {
  return __builtin_elementwise_fma(a, b, c);
}

// DPP lane-permute: executes in the VALU pipe (no LDS round trip).
template <int CTRL>
__device__ __forceinline__ float dppmov(float v) {
  return __int_as_float(__builtin_amdgcn_update_dpp(
      0, __float_as_int(v), CTRL, 0xF, 0xF, true));
}

// xor16 / xor32 lane exchanges. gfx950 permlane*_swap are VALU instructions
// (no LDS pipe); ds_swizzle/shfl fallbacks keep the code portable.
#if __has_builtin(__builtin_amdgcn_permlane16_swap)
__device__ __forceinline__ float sum_x16(float v) {
  u32v2 r = __builtin_amdgcn_permlane16_swap(__float_as_uint(v), __float_as_uint(v), false, false);
  return __uint_as_float(r.x) + __uint_as_float(r.y);
}
__device__ __forceinline__ float max_x16(float v) {
  u32v2 r = __builtin_amdgcn_permlane16_swap(__float_as_uint(v), __float_as_uint(v), false, false);
  return fmaxf(__uint_as_float(r.x), __uint_as_float(r.y));
}
#else
__device__ __forceinline__ float sum_x16(float v) {
  return v + __int_as_float(__builtin_amdgcn_ds_swizzle(__float_as_int(v), 0x401F));
}
__device__ __forceinline__ float max_x16(float v) {
  return fmaxf(v, __int_as_float(__builtin_amdgcn_ds_swizzle(__float_as_int(v), 0x401F)));
}
#endif
#if __has_builtin(__builtin_amdgcn_permlane32_swap)
__device__ __forceinline__ float sum_x32(float v) {
  u32v2 r = __builtin_amdgcn_permlane32_swap(__float_as_uint(v), __float_as_uint(v), false, false);
  return __uint_as_float(r.x) + __uint_as_float(r.y);
}
#else
__device__ __forceinline__ float sum_x32(float v) { return v + __shfl_xor(v, 32, 64); }
#endif

__device__ __forceinline__ float redsum32(float v) {
  v += dppmov<0xB1>(v);    // xor 1 (quad_perm)
  v += dppmov<0x4E>(v);    // xor 2 (quad_perm)
  v += dppmov<0x141>(v);   // xor 7 (row_half_mirror)
  v += dppmov<0x140>(v);   // xor 15 (row_mirror)
  return sum_x16(v);       // xor 16
}
__device__ __forceinline__ float redmax32(float v) {
  v = fmaxf(v, dppmov<0xB1>(v));
  v = fmaxf(v, dppmov<0x4E>(v));
  v = fmaxf(v, dppmov<0x141>(v));
  v = fmaxf(v, dppmov<0x140>(v));
  return max_x16(v);
}

// 4x4 pose matmul on packed f2 lanes: v2[8] = x(4x4) @ w(4x4), row-major.
__device__ __forceinline__ void mat8(const float* __restrict__ xrow,
                                     float4 w0, float4 w1, float4 w2, float4 w3,
                                     f2 (&v2)[8]) {
  const float4* xp = reinterpret_cast<const float4*>(xrow);
  float4 xv0 = xp[0], xv1 = xp[1], xv2_ = xp[2], xv3 = xp[3];
  f2 w0a = {w0.x, w0.y}, w0b = {w0.z, w0.w};
  f2 w1a = {w1.x, w1.y}, w1b = {w1.z, w1.w};
  f2 w2a = {w2.x, w2.y}, w2b = {w2.z, w2.w};
  f2 w3a = {w3.x, w3.y}, w3b = {w3.z, w3.w};
  {
    f2 ta = f2s(xv0.x) * w0a; f2 tb = f2s(xv0.x) * w0b;
    ta = pkfma(f2s(xv0.y), w1a, ta); tb = pkfma(f2s(xv0.y), w1b, tb);
    ta = pkfma(f2s(xv0.z), w2a, ta); tb = pkfma(f2s(xv0.z), w2b, tb);
    v2[0] = pkfma(f2s(xv0.w), w3a, ta); v2[1] = pkfma(f2s(xv0.w), w3b, tb);
  }
  {
    f2 ta = f2s(xv1.x) * w0a; f2 tb = f2s(xv1.x) * w0b;
    ta = pkfma(f2s(xv1.y), w1a, ta); tb = pkfma(f2s(xv1.y), w1b, tb);
    ta = pkfma(f2s(xv1.z), w2a, ta); tb = pkfma(f2s(xv1.z), w2b, tb);
    v2[2] = pkfma(f2s(xv1.w), w3a, ta); v2[3] = pkfma(f2s(xv1.w), w3b, tb);
  }
  {
    f2 ta = f2s(xv2_.x) * w0a; f2 tb = f2s(xv2_.x) * w0b;
    ta = pkfma(f2s(xv2_.y), w1a, ta); tb = pkfma(f2s(xv2_.y), w1b, tb);
    ta = pkfma(f2s(xv2_.z), w2a, ta); tb = pkfma(f2s(xv2_.z), w2b, tb);
    v2[4] = pkfma(f2s(xv2_.w), w3a, ta); v2[5] = pkfma(f2s(xv2_.w), w3b, tb);
  }
  {
    f2 ta = f2s(xv3.x) * w0a; f2 tb = f2s(xv3.x) * w0b;
    ta = pkfma(f2s(xv3.y), w1a, ta); tb = pkfma(f2s(xv3.y), w1b, tb);
    ta = pkfma(f2s(xv3.z), w2a, ta); tb = pkfma(f2s(xv3.z), w2b, tb);
    v2[6] = pkfma(f2s(xv3.w), w3a, ta); v2[7] = pkfma(f2s(xv3.w), w3b, tb);
  }
}

template <bool V> struct BoolC { static constexpr bool value = V; };

// One block per output row n (508 rows). 512 threads = 16 chunks x 32 c.
// Thread (chunk,c) owns output capsule c for B in [chunk*18, chunk*18+18).
//
// All three pass loops are FULLY UNROLLED (trip 18, compile-time): every
// w-load / r-store address becomes a literal offset, the doStore branch is
// a template parameter, and the scheduler gets a whole-pass window to hoist
// loads and fill the redsum dependency shadow (measured VALU time was ~2.8x
// the math-op floor -> the fat was addressing/branch/bookkeeping, not math).
// vbuf parity uses literal indices only (runtime-indexed arrays -> scratch).
//
// launch_bounds(512, 2): empirically caps VGPR at 128 (2 blocks/CU);
// (512,4) forced a 64-cap and spilled (rounds 0-2). Spills show as
// WRITE_SIZE above the 19.4 MB output floor.
__launch_bounds__(512, 2)
__global__ void convcaps_kernel(const float* __restrict__ x,
                                const float* __restrict__ wgl,
                                const float* __restrict__ beta_u,
                                const float* __restrict__ beta_a,
                                float* __restrict__ out) {
  __shared__ float xr[288][16];       // pose patches, 18 KB
  __shared__ float a_sh[288];         // a/(a+EPS)
  __shared__ float red[33][256];      // per-wave partials (A1[16],A2[16],S)
  __shared__ float mu_l[32][18];      // +2 pad: rows 8B-aligned for b64 reads
  __shared__ float i2s_l[32][18];     // LOG2E/(2*sigma)
  __shared__ float hl_l[32][18];      // 0.5*ln(sigma)
  __shared__ float S_l[32];
  __shared__ float aout_l[32];
  __shared__ float lnao_l[32];

  const int tid = threadIdx.x;
  const int n = blockIdx.x;
  const int c = tid & 31;
  const int chunk = tid >> 5;         // 0..15

  // ---- stage 9 source rows (float4): xr[B][s], a_sh[B] ----
  for (int idx = tid; idx < 1224; idx += 512) {   // 9 * 136 float4
    int t = idx / 136;
    int e4 = idx - t * 136;
    int g = 9 * n + t;
    int bg = g / 2286;                 // 2286 = 9*254
    int ki = (g % 2286) / 762;         // 762 = 3*254
    int owp = g % 254;
    const float4* src = reinterpret_cast<const float4*>(x) +
                        (size_t)((bg * 256 + ki + owp) * 4) * 136;
    float4 val = src[e4];
    if (e4 < 128) reinterpret_cast<float4*>(&xr[0][0])[t * 128 + e4] = val;
    else          reinterpret_cast<float4*>(a_sh)[t * 8 + (e4 - 128)] = val;
  }
  __syncthreads();
  for (int e = tid; e < 288; e += 512) { float a = a_sh[e]; a_sh[e] = a / (a + EPS); }
  __syncthreads();

  f2 A1[8], A2[8];
  float Ssum;
  f2 m2[8], i2s2[8];                  // m2 = -2*mu*i2s; i2s pre-scaled LOG2E
  float bias3 = 0.f;
  const int Bbase = chunk * 18;
  const float4* wp = reinterpret_cast<const float4*>(wgl) + ((size_t)(Bbase * 32 + c)) * 4;
  float* rowout = out + 276352 + ((size_t)n * 288 + Bbase) * 32 + c;   // r output

  auto ldw = [&](int i, float4& b0, float4& b1, float4& b2, float4& b3) {
    const float4* nx = wp + (size_t)i * 128;
    b0 = nx[0]; b1 = nx[1]; b2 = nx[2]; b3 = nx[3];
  };

  auto accum = [&](const f2 (&v2)[8], float wgt) {
    f2 wg = f2s(wgt);
    #pragma unroll
    for (int j = 0; j < 8; ++j) {
      f2 p = wg * v2[j];
      A1[j] += p;
      A2[j] = pkfma(p, v2[j], A2[j]);
    }
    Ssum += wgt;
  };

  auto qexp = [&](const f2 (&v2)[8]) -> float {
    f2 qa = {0.f, 0.f}, qb = {0.f, 0.f};
    #pragma unroll
    for (int j = 0; j < 8; j += 2) {
      f2 t0 = pkfma(v2[j], i2s2[j], m2[j]);
      qa = pkfma(v2[j], t0, qa);
      f2 t1 = pkfma(v2[j + 1], i2s2[j + 1], m2[j + 1]);
      qb = pkfma(v2[j + 1], t1, qb);
    }
    float acc = (qa.x + qb.x) + (qa.y + qb.y);
    float lnap = bias3 - acc;           // <= 0, log2 domain
    float e;
    asm("v_exp_f32 %0, %1" : "=v"(e) : "v"(lnap));
    return e;
  };

  auto finalize = [&]() {
    // cross-half pre-reduce (VALU), then LDS across the 8 wave-pairs
    #pragma unroll
    for (int j = 0; j < 8; ++j) {
      A1[j].x = sum_x32(A1[j].x);
      A1[j].y = sum_x32(A1[j].y);
      A2[j].x = sum_x32(A2[j].x);
      A2[j].y = sum_x32(A2[j].y);
    }
    Ssum = sum_x32(Ssum);
    if ((tid & 63) < 32) {
      int col = (tid >> 6) * 32 + c;
      #pragma unroll
      for (int j = 0; j < 8; ++j) {
        red[2 * j][col] = A1[j].x;
        red[2 * j + 1][col] = A1[j].y;
        red[16 + 2 * j][col] = A2[j].x;
        red[17 + 2 * j][col] = A2[j].y;
      }
      red[32][col] = Ssum;
    }
    __syncthreads();
    {
      int s = tid >> 5;
      int c2 = tid & 31;
      float a1 = 0.f, a2 = 0.f, ss = 0.f;
      #pragma unroll
      for (int ch = 0; ch < 8; ++ch) {
        int col = ch * 32 + c2;
        a1 += red[s][col];
        a2 += red[16 + s][col];
        ss += red[32][col];
      }
      float inv = __builtin_amdgcn_rcpf(ss + EPS);
      float m = a1 * inv;
      float Sc = ss * inv;
      float sg = fmaf(-m * m, 2.0f - Sc, a2 * inv) + EPS;   // sigma_sq
      mu_l[c2][s] = m;
      i2s_l[c2][s] = (0.5f * LOG2E) * __builtin_amdgcn_rcpf(sg);  // log2 domain
      hl_l[c2][s] = 0.5f * __logf(sg);
      if (s == 0) S_l[c2] = ss;
    }
    __syncthreads();
    if (tid < 32) {
      float sh = 0.f;
      #pragma unroll
      for (int s = 0; s < 16; ++s) sh += hl_l[tid][s];
      float cost = fmaf(beta_u[tid], 16.0f, sh) * S_l[tid];
      float z = LAMBDA * (beta_a[tid] - cost);
      float ao = __builtin_amdgcn_rcpf(1.0f + __expf(-z));
      aout_l[tid] = ao;
      lnao_l[tid] = __logf(ao);
    }
    __syncthreads();
  };

  // ================= pass 0: wgt = a/32, no softmax =================
  {
    #pragma unroll
    for (int j = 0; j < 8; ++j) { A1[j] = (f2){0.f, 0.f}; A2[j] = (f2){0.f, 0.f}; }
    Ssum = 0.f;
    #pragma unroll
    for (int i = 0; i < 18; ++i) {
      float4 w0, w1, w2, w3;
      ldw(i, w0, w1, w2, w3);
      f2 v2[8];
      mat8(&xr[Bbase + i][0], w0, w1, w2, w3, v2);
      accum(v2, a_sh[Bbase + i] * 0.03125f);
    }
    finalize();
  }

  // ================= passes 1,2: fully-unrolled softmax loop =================
  auto em_pass = [&](auto storeC) {
    constexpr bool doStore = decltype(storeC)::value;
    #pragma unroll
    for (int j = 0; j < 8; ++j) { A1[j] = (f2){0.f, 0.f}; A2[j] = (f2){0.f, 0.f}; }
    Ssum = 0.f;
    {
      const f2* murow = reinterpret_cast<const f2*>(&mu_l[c][0]);
      const f2* isrow = reinterpret_cast<const f2*>(&i2s_l[c][0]);
      f2 kacc = {0.f, 0.f};
      float Hl = 0.f;
      #pragma unroll
      for (int j = 0; j < 8; ++j) {
        f2 mu = murow[j];
        f2 is = isrow[j];
        i2s2[j] = is;
        f2 mis = mu * is;
        m2[j] = f2s(-2.f) * mis;
        kacc = pkfma(mis, mu, kacc);        // sum mu^2*i2s (log2 domain)
        Hl += hl_l[c][2 * j] + hl_l[c][2 * j + 1];
      }
      float bias = lnao_l[c] - Hl;
      bias -= redmax32(bias);               // once per pass: lnap <= 0 always
      bias3 = bias * LOG2E - (kacc.x + kacc.y);
    }

    f2 vb0[8], vb1[8];                      // parity banks, literal-indexed
    float wg0 = 0.f, wg1 = 0.f;
    #pragma unroll
    for (int i = 0; i < 18; ++i) {          // i is a literal after unroll
      f2 (&v2)[8] = (i & 1) ? vb1 : vb0;
      float4 w0, w1, w2, w3;
      ldw(i, w0, w1, w2, w3);
      mat8(&xr[Bbase + i][0], w0, w1, w2, w3, v2);
      float af = a_sh[Bbase + i];
      float e = qexp(v2);
      float se = redsum32(e);
      if (i > 0) {                          // fill the reduce's dep shadow
        f2 (&pv)[8] = ((i - 1) & 1) ? vb1 : vb0;
        accum(pv, ((i - 1) & 1) ? wg1 : wg0);
      }
      float t = __builtin_amdgcn_rcpf(se + 1e-35f);
      float r2 = e * t;
      if (doStore) rowout[(size_t)i * 32] = r2;
      ((i & 1) ? wg1 : wg0) = r2 * af;
    }
    accum(vb1, wg1);                        // i = 17 is odd -> bank 1
    finalize();
  };
  em_pass(BoolC<false>{});
  em_pass(BoolC<true>{});

  // ---- outputs: row n = [mu (512) | a_out (32)], coalesced ----
  {
    int c2 = tid >> 4;
    int s = tid & 15;
    out[(size_t)n * 544 + tid] = mu_l[c2][s];
  }
  if (tid < 32) out[(size_t)n * 544 + 512 + tid] = aout_l[tid];
}

extern "C" void kernel_launch(void* const* d_in, const int* in_sizes, int n_in,
                              void* d_out, int out_size, void* d_ws, size_t ws_size,
                              hipStream_t stream) {
  const float* x  = (const float*)d_in[0];
  const float* w  = (const float*)d_in[1];
  const float* bu = (const float*)d_in[2];
  const float* ba = (const float*)d_in[3];
  float* out = (float*)d_out;
  convcaps_kernel<<<dim3(508), dim3(512), 0, stream>>>(x, w, bu, ba, out);
}